// Round 8
// baseline (153.858 us; speedup 1.0000x reference)
//
#include <hip/hip_runtime.h>

#define EPSV 0.001f
#define NCTX 16
#define DIM  64
#define NSLICE 16
#define PART_STRIDE 2080   // floats per partial block: s1[1024] s2[1024] cnt[16] pad
#define P2_STRIDE   132    // per (ctx,slice): s1[64] s2[64] cnt[1] pad

// ws layout (floats): [0,1024) scale; [1024,2048) shift;
// [2048, 2048+nb*PART_STRIDE) stage-1 partials; then 16*16*P2_STRIDE stage-2.
#define WS_SCALE 0
#define WS_SHIFT 1024
#define WS_PART  2048

#define STATS_BLOCKS 1280   // 32KB LDS/block -> 5 blocks/CU = 160KB (exact fit)

typedef float v4f __attribute__((ext_vector_type(4)));

// ---------------- Pass 1: private-LDS RMW + chunked batched loads ----------------
// MEASURED: global fp CAS 650us (r1), LDS fp CAS 645us (r5), scalar-branch switch
// ~95us (r2), LDS RMW + guarded rotating pipeline ~100us (r3/r4), register one-hot
// 236us (r6: 16x VALU + VGPR>128 cliff). Winner (r7): collision-free per-wave LDS
// float2{s1,s2} RMW (in-wave DS ordering = correct, no atomics, no branches) +
// contiguous per-wave row ranges with straight-line chunk-of-8 clamped loads
// (weight-neutralized tail) -> compiler batches 8 loads, counted vmcnt, real MLP.
__global__ __launch_bounds__(256) void stats_kernel(
    const float* __restrict__ samples,
    const int* __restrict__ contexts,
    float* __restrict__ part, int N, int rpw) {
  __shared__ float2 sacc2[4][NCTX * DIM];   // 32 KB: per-wave {s1,s2}
  __shared__ float  cshare[4][NCTX];

  int tid  = threadIdx.x;
  int lane = tid & 63;
  int wv   = tid >> 6;

  float2* zz = &sacc2[0][0];
  for (int i = tid; i < 4 * NCTX * DIM; i += 256) zz[i] = make_float2(0.f, 0.f);
  __syncthreads();

  float2* m = sacc2[wv];
  float cnl = 0.f;   // lane L counts rows with c==L (L<16 meaningful)

  int wid   = blockIdx.x * 4 + wv;
  int start = wid * rpw;
  int end   = min(N, start + rpw);

  for (int base = start; base < end; base += 8) {
    float vv[8]; int cc[8]; float wt[8];
#pragma unroll
    for (int p = 0; p < 8; ++p) {
      int r  = base + p;
      int rc = min(r, N - 1);
      vv[p] = samples[(size_t)rc * DIM + lane];
      cc[p] = contexts[rc];                  // wave-uniform address
      wt[p] = (r < end) ? 1.f : 0.f;         // tail/overlap neutralizer
    }
#pragma unroll
    for (int p = 0; p < 8; ++p) {
      int   cp = cc[p];
      float w  = wt[p];
      float v  = vv[p];
      float vw = v * w;
      float2 t = m[cp * DIM + lane];
      t.x += vw;                     // s1 += v (or 0)
      t.y = fmaf(vw, v, t.y);        // s2 += v*v (or 0)
      m[cp * DIM + lane] = t;
      cnl += (lane == cp) ? w : 0.f;
    }
  }

  __syncthreads();

  // block-reduce the 4 per-wave regions, write partials
  float* pb = part + (size_t)blockIdx.x * PART_STRIDE;
  for (int i = tid; i < NCTX * DIM; i += 256) {
    float2 a0 = sacc2[0][i];
    float2 a1 = sacc2[1][i];
    float2 a2 = sacc2[2][i];
    float2 a3 = sacc2[3][i];
    pb[i]        = a0.x + a1.x + a2.x + a3.x;
    pb[1024 + i] = a0.y + a1.y + a2.y + a3.y;
  }
  if (lane < NCTX) cshare[wv][lane] = cnl;
  __syncthreads();
  if (tid < NCTX)
    pb[2048 + tid] = cshare[0][tid] + cshare[1][tid] +
                     cshare[2][tid] + cshare[3][tid];
}

// ------------- Pass 2a: tree-reduce partials (all CUs active) -------------
__global__ __launch_bounds__(256) void reduce_a_kernel(
    const float* __restrict__ part, float* __restrict__ part2, int nb) {
  int c     = blockIdx.x & (NCTX - 1);
  int slice = blockIdx.x >> 4;
  int tid = threadIdx.x, d = tid & 63, g = tid >> 6;
  int per = nb / NSLICE;
  int b0  = slice * per;

  float a1 = 0.f, a2 = 0.f, ac = 0.f;
  float b1 = 0.f, b2 = 0.f, bc = 0.f;
  for (int b = b0 + g; b < b0 + per; b += 8) {
    const float* p = part + (size_t)b * PART_STRIDE;
    a1 += p[c * DIM + d];
    a2 += p[1024 + c * DIM + d];
    if (d == 0) ac += p[2048 + c];
    int bb = b + 4;
    if (bb < b0 + per) {
      const float* q = part + (size_t)bb * PART_STRIDE;
      b1 += q[c * DIM + d];
      b2 += q[1024 + c * DIM + d];
      if (d == 0) bc += q[2048 + c];
    }
  }
  a1 += b1; a2 += b2; ac += bc;

  __shared__ float r1[4][DIM], r2[4][DIM], rc[4];
  r1[g][d] = a1;
  r2[g][d] = a2;
  if (d == 0) rc[g] = ac;
  __syncthreads();

  if (tid < DIM) {
    float* o = part2 + (size_t)(c * NSLICE + slice) * P2_STRIDE;
    o[tid]      = r1[0][tid] + r1[1][tid] + r1[2][tid] + r1[3][tid];
    o[64 + tid] = r2[0][tid] + r2[1][tid] + r2[2][tid] + r2[3][tid];
    if (tid == 0) o[128] = rc[0] + rc[1] + rc[2] + rc[3];
  }
}

// ------------- Pass 2b: final 16-way sum + scale/shift finalize -------------
__global__ __launch_bounds__(64) void finalize_kernel(
    const float* __restrict__ part2,
    const float* __restrict__ gamma,
    const float* __restrict__ beta,
    const float* __restrict__ priors,
    float* __restrict__ ws) {
  int c = blockIdx.x;
  int d = threadIdx.x;
  float s1 = 0.f, s2 = 0.f, cnt = 0.f;
#pragma unroll
  for (int s = 0; s < NSLICE; ++s) {
    const float* p = part2 + (size_t)(c * NSLICE + s) * P2_STRIDE;
    s1  += p[d];
    s2  += p[64 + d];
    cnt += p[128];
  }
  float safe = fmaxf(cnt, 1.f);
  float mean = s1 / safe;
  float var  = s2 / safe - mean * mean;
  float istd = rsqrtf(var + EPSV);
  float ps   = rsqrtf(priors[c]);
  float gm   = gamma[c * DIM + d];
  float scale = gm * istd * ps;
  float shift = (beta[c * DIM + d] - gm * mean * istd) * ps;
  if (!(cnt > 0.f)) { scale = 1.f; shift = 0.f; }  // where(cnt>0, y, x)
  ws[WS_SCALE + c * DIM + d] = scale;
  ws[WS_SHIFT + c * DIM + d] = shift;
}

// ---------------- Pass 3: y = x * scale[c] + shift[c] ----------------
// MEASURED (r4 vs r7): forward/reverse/nt-load variants all ~83us -- the
// Infinity Cache is memory-side with ~random replacement (hit ~= cap/footprint
// ~= 256/480 ~= 53%, order-independent), so no ordering tricks: plain forward
// grid-stride, temporal loads, nt stores (out is dead data for later kernels).
__global__ __launch_bounds__(256) void norm_kernel(
    const v4f* __restrict__ samples4,
    const int* __restrict__ contexts,
    const float* __restrict__ ws,
    v4f* __restrict__ out4, int n4) {
  __shared__ v4f sc[NCTX * DIM / 4];
  __shared__ v4f sh[NCTX * DIM / 4];
  const v4f* wsc = (const v4f*)(ws + WS_SCALE);
  const v4f* wsh = (const v4f*)(ws + WS_SHIFT);
  for (int i = threadIdx.x; i < NCTX * DIM / 4; i += blockDim.x) {
    sc[i] = wsc[i];
    sh[i] = wsh[i];
  }
  __syncthreads();

  int stride = gridDim.x * blockDim.x;
  for (int i = blockIdx.x * blockDim.x + threadIdx.x; i < n4; i += stride) {
    v4f v = samples4[i];
    int row = i >> 4;          // 16 v4f per row (D=64)
    int d4  = i & 15;
    int c   = contexts[row];
    v4f r = v * sc[c * 16 + d4] + sh[c * 16 + d4];
    __builtin_nontemporal_store(r, &out4[i]);
  }
}

extern "C" void kernel_launch(void* const* d_in, const int* in_sizes, int n_in,
                              void* d_out, int out_size, void* d_ws, size_t ws_size,
                              hipStream_t stream) {
  const float* samples  = (const float*)d_in[0];
  const int*   contexts = (const int*)d_in[1];
  const float* gamma    = (const float*)d_in[2];
  const float* beta     = (const float*)d_in[3];
  const float* priors   = (const float*)d_in[4];
  float* out = (float*)d_out;
  float* ws  = (float*)d_ws;

  int N = in_sizes[1];  // contexts has N elements

  int nb = STATS_BLOCKS;
  int nwaves = nb * 4;
  int rpw = ((N + nwaves - 1) / nwaves + 7) & ~7;   // rows/wave, multiple of 8

  float* part  = ws + WS_PART;
  float* part2 = part + (size_t)nb * PART_STRIDE;

  stats_kernel<<<nb, 256, 0, stream>>>(samples, contexts, part, N, rpw);
  reduce_a_kernel<<<NCTX * NSLICE, 256, 0, stream>>>(part, part2, nb);
  finalize_kernel<<<NCTX, 64, 0, stream>>>(part2, gamma, beta, priors, ws);

  int n4 = N * (DIM / 4);
  norm_kernel<<<2048, 256, 0, stream>>>((const v4f*)samples, contexts, ws,
                                        (v4f*)out, n4);
}

// Round 9
// 138.941 us; speedup vs baseline: 1.1074x; 1.1074x over previous
//
#include <hip/hip_runtime.h>

#define EPSV 0.001f
#define NCTX 16
#define DIM  64
#define NSLICE 16
#define PART_STRIDE 2080   // floats per partial block: s1[1024] s2[1024] cnt[16] pad
#define P2_STRIDE   132    // per (ctx,slice): s1[64] s2[64] cnt[1] pad

// ws layout (floats): [0,1024) scale; [1024,2048) shift;
// [2048, 2048+nb*PART_STRIDE) stage-1 partials; then 16*16*P2_STRIDE stage-2.
#define WS_SCALE 0
#define WS_SHIFT 1024
#define WS_PART  2048

// LDS/block = 33,024 B (32KB sacc2 + 256B cshare) -> 4 blocks/CU (NOT 5:
// 5x33024 > 160KiB -- r8's 1280-block "exact fit" was wrong and cost a
// straggler generation, +14us). 1024 blocks = one balanced generation.
#define STATS_BLOCKS 1024

typedef float v4f __attribute__((ext_vector_type(4)));

// ---------------- Pass 1: private-LDS RMW + chunked batched loads ----------------
// MEASURED: global fp CAS 650us (r1), LDS fp CAS 645us (r5), scalar-branch switch
// ~95us (r2), LDS RMW + guarded rotating pipeline ~100us (r3/r4), register one-hot
// 236us (r6: 16x VALU + VGPR>128 cliff). Winner (r7, 140us total): collision-free
// per-wave LDS float2{s1,s2} RMW (in-wave DS ordering = correct, no atomics, no
// branches) + contiguous per-wave row ranges with straight-line chunk-of-8 clamped
// loads (weight-neutralized tail) -> compiler batches 8 loads, counted vmcnt, MLP.
__global__ __launch_bounds__(256) void stats_kernel(
    const float* __restrict__ samples,
    const int* __restrict__ contexts,
    float* __restrict__ part, int N, int rpw) {
  __shared__ float2 sacc2[4][NCTX * DIM];   // 32 KB: per-wave {s1,s2}
  __shared__ float  cshare[4][NCTX];

  int tid  = threadIdx.x;
  int lane = tid & 63;
  int wv   = tid >> 6;

  float2* zz = &sacc2[0][0];
  for (int i = tid; i < 4 * NCTX * DIM; i += 256) zz[i] = make_float2(0.f, 0.f);
  __syncthreads();

  float2* m = sacc2[wv];
  float cnl = 0.f;   // lane L counts rows with c==L (L<16 meaningful)

  int wid   = blockIdx.x * 4 + wv;
  int start = wid * rpw;
  int end   = min(N, start + rpw);

  for (int base = start; base < end; base += 8) {
    float vv[8]; int cc[8]; float wt[8];
#pragma unroll
    for (int p = 0; p < 8; ++p) {
      int r  = base + p;
      int rc = min(r, N - 1);
      vv[p] = samples[(size_t)rc * DIM + lane];
      cc[p] = contexts[rc];                  // wave-uniform address
      wt[p] = (r < end) ? 1.f : 0.f;         // tail/overlap neutralizer
    }
#pragma unroll
    for (int p = 0; p < 8; ++p) {
      int   cp = cc[p];
      float w  = wt[p];
      float v  = vv[p];
      float vw = v * w;
      float2 t = m[cp * DIM + lane];
      t.x += vw;                     // s1 += v (or 0)
      t.y = fmaf(vw, v, t.y);        // s2 += v*v (or 0)
      m[cp * DIM + lane] = t;
      cnl += (lane == cp) ? w : 0.f;
    }
  }

  __syncthreads();

  // block-reduce the 4 per-wave regions, write partials
  float* pb = part + (size_t)blockIdx.x * PART_STRIDE;
  for (int i = tid; i < NCTX * DIM; i += 256) {
    float2 a0 = sacc2[0][i];
    float2 a1 = sacc2[1][i];
    float2 a2 = sacc2[2][i];
    float2 a3 = sacc2[3][i];
    pb[i]        = a0.x + a1.x + a2.x + a3.x;
    pb[1024 + i] = a0.y + a1.y + a2.y + a3.y;
  }
  if (lane < NCTX) cshare[wv][lane] = cnl;
  __syncthreads();
  if (tid < NCTX)
    pb[2048 + tid] = cshare[0][tid] + cshare[1][tid] +
                     cshare[2][tid] + cshare[3][tid];
}

// ------------- Pass 2a: tree-reduce partials (all CUs active) -------------
__global__ __launch_bounds__(256) void reduce_a_kernel(
    const float* __restrict__ part, float* __restrict__ part2, int nb) {
  int c     = blockIdx.x & (NCTX - 1);
  int slice = blockIdx.x >> 4;
  int tid = threadIdx.x, d = tid & 63, g = tid >> 6;
  int per = nb / NSLICE;
  int b0  = slice * per;

  float a1 = 0.f, a2 = 0.f, ac = 0.f;
  float b1 = 0.f, b2 = 0.f, bc = 0.f;
  for (int b = b0 + g; b < b0 + per; b += 8) {
    const float* p = part + (size_t)b * PART_STRIDE;
    a1 += p[c * DIM + d];
    a2 += p[1024 + c * DIM + d];
    if (d == 0) ac += p[2048 + c];
    int bb = b + 4;
    if (bb < b0 + per) {
      const float* q = part + (size_t)bb * PART_STRIDE;
      b1 += q[c * DIM + d];
      b2 += q[1024 + c * DIM + d];
      if (d == 0) bc += q[2048 + c];
    }
  }
  a1 += b1; a2 += b2; ac += bc;

  __shared__ float r1[4][DIM], r2[4][DIM], rc[4];
  r1[g][d] = a1;
  r2[g][d] = a2;
  if (d == 0) rc[g] = ac;
  __syncthreads();

  if (tid < DIM) {
    float* o = part2 + (size_t)(c * NSLICE + slice) * P2_STRIDE;
    o[tid]      = r1[0][tid] + r1[1][tid] + r1[2][tid] + r1[3][tid];
    o[64 + tid] = r2[0][tid] + r2[1][tid] + r2[2][tid] + r2[3][tid];
    if (tid == 0) o[128] = rc[0] + rc[1] + rc[2] + rc[3];
  }
}

// ------------- Pass 2b: final 16-way sum + scale/shift finalize -------------
__global__ __launch_bounds__(64) void finalize_kernel(
    const float* __restrict__ part2,
    const float* __restrict__ gamma,
    const float* __restrict__ beta,
    const float* __restrict__ priors,
    float* __restrict__ ws) {
  int c = blockIdx.x;
  int d = threadIdx.x;
  float s1 = 0.f, s2 = 0.f, cnt = 0.f;
#pragma unroll
  for (int s = 0; s < NSLICE; ++s) {
    const float* p = part2 + (size_t)(c * NSLICE + s) * P2_STRIDE;
    s1  += p[d];
    s2  += p[64 + d];
    cnt += p[128];
  }
  float safe = fmaxf(cnt, 1.f);
  float mean = s1 / safe;
  float var  = s2 / safe - mean * mean;
  float istd = rsqrtf(var + EPSV);
  float ps   = rsqrtf(priors[c]);
  float gm   = gamma[c * DIM + d];
  float scale = gm * istd * ps;
  float shift = (beta[c * DIM + d] - gm * mean * istd) * ps;
  if (!(cnt > 0.f)) { scale = 1.f; shift = 0.f; }  // where(cnt>0, y, x)
  ws[WS_SCALE + c * DIM + d] = scale;
  ws[WS_SHIFT + c * DIM + d] = shift;
}

// ---------------- Pass 3: y = x * scale[c] + shift[c] ----------------
// MEASURED (r4/r7/r8): norm runs at ~6.2 TB/s DEMAND bandwidth (516 MB
// read+write / ~83us) = the m13 copy ceiling. L3 hits don't beat the fabric
// limit, so ordering/nt variants are equivalent. Keep the measured-140us form.
__global__ __launch_bounds__(256) void norm_kernel(
    const v4f* __restrict__ samples4,
    const int* __restrict__ contexts,
    const float* __restrict__ ws,
    v4f* __restrict__ out4, int n4) {
  __shared__ v4f sc[NCTX * DIM / 4];
  __shared__ v4f sh[NCTX * DIM / 4];
  const v4f* wsc = (const v4f*)(ws + WS_SCALE);
  const v4f* wsh = (const v4f*)(ws + WS_SHIFT);
  for (int i = threadIdx.x; i < NCTX * DIM / 4; i += blockDim.x) {
    sc[i] = wsc[i];
    sh[i] = wsh[i];
  }
  __syncthreads();

  int gid    = blockIdx.x * blockDim.x + threadIdx.x;
  int stride = gridDim.x * blockDim.x;
  if (gid >= n4) return;
  int niter = (n4 - gid + stride - 1) / stride;
  for (int k = niter - 1; k >= 0; --k) {
    int i = k * stride + gid;
    v4f v = __builtin_nontemporal_load(&samples4[i]);
    int row = i >> 4;          // 16 v4f per row (D=64)
    int d4  = i & 15;
    int c   = contexts[row];
    v4f r = v * sc[c * 16 + d4] + sh[c * 16 + d4];
    __builtin_nontemporal_store(r, &out4[i]);
  }
}

extern "C" void kernel_launch(void* const* d_in, const int* in_sizes, int n_in,
                              void* d_out, int out_size, void* d_ws, size_t ws_size,
                              hipStream_t stream) {
  const float* samples  = (const float*)d_in[0];
  const int*   contexts = (const int*)d_in[1];
  const float* gamma    = (const float*)d_in[2];
  const float* beta     = (const float*)d_in[3];
  const float* priors   = (const float*)d_in[4];
  float* out = (float*)d_out;
  float* ws  = (float*)d_ws;

  int N = in_sizes[1];  // contexts has N elements

  int nb = STATS_BLOCKS;
  int nwaves = nb * 4;
  int rpw = ((N + nwaves - 1) / nwaves + 7) & ~7;   // rows/wave, multiple of 8

  float* part  = ws + WS_PART;
  float* part2 = part + (size_t)nb * PART_STRIDE;

  stats_kernel<<<nb, 256, 0, stream>>>(samples, contexts, part, N, rpw);
  reduce_a_kernel<<<NCTX * NSLICE, 256, 0, stream>>>(part, part2, nb);
  finalize_kernel<<<NCTX, 64, 0, stream>>>(part2, gamma, beta, priors, ws);

  int n4 = N * (DIM / 4);
  norm_kernel<<<4096, 256, 0, stream>>>((const v4f*)samples, contexts, ws,
                                        (v4f*)out, n4);
}